// Round 1
// baseline (401.600 us; speedup 1.0000x reference)
//
#include <hip/hip_runtime.h>
#include <math.h>

// Problem constants (fixed by reference setup_inputs)
#define NG   8192      // groups
#define NS   64        // samples per group
#define ND   128       // feature dim
#define NH   256       // hidden dim
#define NO   10        // K+2 outputs of layer 2
#define GPB  16        // groups per block in MLP kernel

// ---------------------------------------------------------------------------
// Kernel 1: per-group stats -> rep.  One block per group, 256 threads.
// Thread t: c = t&31 (float4 column, dims 4c..4c+3), r = t>>5 (sample octet).
// Memory-bound: streams 256 MB of x once, coalesced float4.
// ---------------------------------------------------------------------------
__global__ __launch_bounds__(256) void stats_kernel(
    const float* __restrict__ x, const float* __restrict__ y,
    const float* __restrict__ ax, const float* __restrict__ ay,
    float* __restrict__ rep)
{
    const int g = blockIdx.x;
    const int t = threadIdx.x;
    const int c = t & 31;
    const int r = t >> 5;

    __shared__ float  yL[NS];
    __shared__ float4 axL[32];
    __shared__ float4 sxL[8][32];
    __shared__ float4 sxyL[8][32];
    __shared__ float  sxxL[256];

    if (t < NS) {
        yL[t] = y[g * NS + t] - ay[g];
    } else if (t < NS + 32) {
        axL[t - NS] = ((const float4*)ax)[g * 32 + (t - NS)];
    }
    __syncthreads();

    const float4 a4 = axL[c];
    const float4* xg = (const float4*)x + (size_t)g * (NS * 32) + r * (8 * 32) + c;

    float sx0 = 0.f, sx1 = 0.f, sx2 = 0.f, sx3 = 0.f;
    float sy0 = 0.f, sy1 = 0.f, sy2 = 0.f, sy3 = 0.f;
    float sxx = 0.f;
#pragma unroll
    for (int i = 0; i < 8; ++i) {
        float4 xv = xg[i * 32];
        float yr = yL[r * 8 + i];
        float x0 = xv.x - a4.x;
        float x1 = xv.y - a4.y;
        float x2 = xv.z - a4.z;
        float x3 = xv.w - a4.w;
        sx0 += x0; sx1 += x1; sx2 += x2; sx3 += x3;
        sy0 += x0 * yr; sy1 += x1 * yr; sy2 += x2 * yr; sy3 += x3 * yr;
        sxx += x0 * x0 + x1 * x1 + x2 * x2 + x3 * x3;
    }
    sxL[r][c]  = make_float4(sx0, sx1, sx2, sx3);
    sxyL[r][c] = make_float4(sy0, sy1, sy2, sy3);
    sxxL[t] = sxx;
    __syncthreads();

    if (t < 32) {
        float4 sxv  = sxL[0][t];
        float4 sxyv = sxyL[0][t];
        float  sxxs = sxxL[t];
#pragma unroll
        for (int rr = 1; rr < 8; ++rr) {
            float4 a = sxL[rr][t];
            float4 b = sxyL[rr][t];
            sxv.x += a.x; sxv.y += a.y; sxv.z += a.z; sxv.w += a.w;
            sxyv.x += b.x; sxyv.y += b.y; sxyv.z += b.z; sxyv.w += b.w;
            sxxs += sxxL[rr * 32 + t];
        }
        float tot = sxv.x + sxv.y + sxv.z + sxv.w;
        float sy  = yL[t] + yL[t + 32];
        // butterfly over lanes 0..31 (all in wave 0)
#pragma unroll
        for (int off = 16; off >= 1; off >>= 1) {
            tot  += __shfl_xor(tot, off);
            sxxs += __shfl_xor(sxxs, off);
            sy   += __shfl_xor(sy, off);
        }
        // var = (sxx - tot^2/(n*D)) / (n*D - 1)
        float var = (sxxs - tot * tot * (1.0f / 8192.0f)) * (1.0f / 8191.0f);
        float iv = 1.0f / var;
        float c0 = sy * (1.0f / 64.0f);   // sy / n
        float4 rp;
        rp.x = (sxyv.x - sxv.x * c0) * (1.0f / 63.0f) * iv;
        rp.y = (sxyv.y - sxv.y * c0) * (1.0f / 63.0f) * iv;
        rp.z = (sxyv.z - sxv.z * c0) * (1.0f / 63.0f) * iv;
        rp.w = (sxyv.w - sxv.w * c0) * (1.0f / 63.0f) * iv;
        ((float4*)rep)[g * 32 + t] = rp;
    }
}

// ---------------------------------------------------------------------------
// Kernel 2: MLP head.  512 blocks x 256 threads, GPB=16 groups per block.
// Thread j = hidden unit; W1 row loads coalesced, reused 16x in registers.
// ---------------------------------------------------------------------------
__device__ __forceinline__ float fast_tanh(float v) {
    v = fminf(15.0f, fmaxf(-15.0f, v));
    float e = __expf(2.0f * v);
    return (e - 1.0f) / (e + 1.0f);
}

__device__ __forceinline__ float softplus_f(float v) {
    if (v > 15.0f) return v;
    return log1pf(__expf(v));
}

__global__ __launch_bounds__(256) void mlp_kernel(
    const float* __restrict__ rep, const float* __restrict__ W1,
    const float* __restrict__ b1, const float* __restrict__ W2,
    const float* __restrict__ b2, float* __restrict__ mix,
    float* __restrict__ scl, float* __restrict__ alp,
    float* __restrict__ bet)
{
    const int g0 = blockIdx.x * GPB;
    const int t = threadIdx.x;

    __shared__ __align__(16) float repL[GPB][ND];
    __shared__ float hL[GPB][NH + 1];     // +1 pad: kills 16-way bank conflict
    __shared__ float w2L[NH * NO];
    __shared__ float outL[GPB][NO];

    // stage rep tile: 2048 floats = 512 float4
    {
        const float4* rp4 = (const float4*)(rep + (size_t)g0 * ND);
        float4* dst = (float4*)&repL[0][0];
        dst[t] = rp4[t];
        dst[t + 256] = rp4[t + 256];
    }
    for (int i = t; i < NH * NO; i += 256) w2L[i] = W2[i];
    __syncthreads();

    // layer 1: h[g][t] = tanh(b1[t] + sum_d rep[g][d] * W1[d][t])
    float acc[GPB];
#pragma unroll
    for (int g = 0; g < GPB; ++g) acc[g] = 0.f;

    for (int d = 0; d < ND; d += 4) {
        float w0 = W1[(d + 0) * NH + t];
        float w1 = W1[(d + 1) * NH + t];
        float w2 = W1[(d + 2) * NH + t];
        float w3 = W1[(d + 3) * NH + t];
#pragma unroll
        for (int g = 0; g < GPB; ++g) {
            const float4 r4 = *(const float4*)&repL[g][d];   // wave-uniform broadcast
            acc[g] += r4.x * w0 + r4.y * w1 + r4.z * w2 + r4.w * w3;
        }
    }
    const float bb = b1[t];
#pragma unroll
    for (int g = 0; g < GPB; ++g) {
        hL[g][t] = fast_tanh(acc[g] + bb);
    }
    __syncthreads();

    // layer 2: 160 threads, one (group, output) pair each
    if (t < GPB * NO) {
        const int g = t / NO;
        const int k = t - g * NO;
        float s = b2[k];
#pragma unroll 8
        for (int j = 0; j < NH; ++j) s += hL[g][j] * w2L[j * NO + k];
        outL[g][k] = s;
    }
    __syncthreads();

    // epilogue: one thread per group
    if (t < GPB) {
        const int gg = g0 + t;
        float al = softplus_f(outL[t][0]) * 0.99f + 0.01f;
        float be = softplus_f(outL[t][1]) * 0.99f + 0.01f;
        float m = -1e30f;
#pragma unroll
        for (int k = 0; k < 8; ++k) m = fmaxf(m, outL[t][2 + k]);
        float e[8];
        float sum = 0.f;
#pragma unroll
        for (int k = 0; k < 8; ++k) { e[k] = __expf(outL[t][2 + k] - m); sum += e[k]; }
        float inv = 1.0f / sum;
#pragma unroll
        for (int k = 0; k < 8; ++k) mix[gg * 8 + k] = e[k] * inv;
        alp[gg] = al;
        bet[gg] = be;
        scl[gg] = sqrtf(be / al);
    }
}

// ---------------------------------------------------------------------------
extern "C" void kernel_launch(void* const* d_in, const int* in_sizes, int n_in,
                              void* d_out, int out_size, void* d_ws, size_t ws_size,
                              hipStream_t stream) {
    // inputs: 0=index (unused: groups are contiguous, 64 each), 1=x, 2=y,
    // 3=anchor_x, 4=anchor_y, 5=W1, 6=b1, 7=W2, 8=b2
    const float* x  = (const float*)d_in[1];
    const float* y  = (const float*)d_in[2];
    const float* ax = (const float*)d_in[3];
    const float* ay = (const float*)d_in[4];
    const float* W1 = (const float*)d_in[5];
    const float* b1 = (const float*)d_in[6];
    const float* W2 = (const float*)d_in[7];
    const float* b2 = (const float*)d_in[8];

    float* out = (float*)d_out;
    float* rep = out;                               // [G,128]
    float* mix = out + (size_t)NG * ND;             // [G,8]
    float* scl = mix + (size_t)NG * 8;              // [G,1]
    float* alp = scl + NG;                          // [G,1]
    float* bet = alp + NG;                          // [G,1]

    stats_kernel<<<NG, 256, 0, stream>>>(x, y, ax, ay, rep);
    mlp_kernel<<<NG / GPB, 256, 0, stream>>>(rep, W1, b1, W2, b2, mix, scl, alp, bet);
}

// Round 2
// 400.025 us; speedup vs baseline: 1.0039x; 1.0039x over previous
//
#include <hip/hip_runtime.h>
#include <math.h>

// Problem constants (fixed by reference setup_inputs)
#define NG   8192      // groups
#define NS   64        // samples per group
#define ND   128       // feature dim
#define NH   256       // hidden dim
#define NO   10        // K+2 outputs of layer 2
#define GPB  16        // groups per block in MLP kernel
#define WPB  4         // waves per block in stats kernel

// ---------------------------------------------------------------------------
// Kernel 1: per-group stats -> rep.  ONE WAVE PER GROUP, barrier-free.
// Lane l: c = l&31 (float4 column, dims 4c..4c+3), half = l>>5 (rows 32h..32h+31).
// 32 independent float4 loads per lane (8 in flight), reductions via shfl only.
// Streams 256 MB of x once; goal: HBM-bound (~45 us).
// ---------------------------------------------------------------------------
__global__ __launch_bounds__(256) void stats_kernel(
    const float* __restrict__ x, const float* __restrict__ y,
    const float* __restrict__ ax, const float* __restrict__ ay,
    float* __restrict__ rep)
{
    const int t    = threadIdx.x;
    const int w    = t >> 6;          // wave within block
    const int l    = t & 63;          // lane
    const int g    = blockIdx.x * WPB + w;
    const int c    = l & 31;          // float4 column
    const int half = l >> 5;          // row half (0: rows 0-31, 1: rows 32-63)

    __shared__ float yrelL[WPB][NS];  // per-wave y_rel staging (wave-synchronous)

    // y_rel: coalesced 256B load per wave; ay[g] is a wave-uniform broadcast.
    float yv = y[g * NS + l] - ay[g];
    yrelL[w][l] = yv;                 // same wave writes & reads -> no barrier

    const float4 a4 = ((const float4*)ax)[g * 32 + c];
    const float4* xg = (const float4*)x
                     + (size_t)g * (NS * 32) + (size_t)(half * 32) * 32 + c;

    float4 sx  = make_float4(0.f, 0.f, 0.f, 0.f);
    float4 sxy = make_float4(0.f, 0.f, 0.f, 0.f);
    float  sxx = 0.f;

#pragma unroll
    for (int ii = 0; ii < 4; ++ii) {
        float4 xv[8];
#pragma unroll
        for (int j = 0; j < 8; ++j) xv[j] = xg[(ii * 8 + j) * 32];
#pragma unroll
        for (int j = 0; j < 8; ++j) {
            const float yr = yrelL[w][half * 32 + ii * 8 + j];  // 2-addr broadcast, free
            const float x0 = xv[j].x - a4.x;
            const float x1 = xv[j].y - a4.y;
            const float x2 = xv[j].z - a4.z;
            const float x3 = xv[j].w - a4.w;
            sx.x += x0; sx.y += x1; sx.z += x2; sx.w += x3;
            sxy.x += x0 * yr; sxy.y += x1 * yr; sxy.z += x2 * yr; sxy.w += x3 * yr;
            sxx += x0 * x0 + x1 * x1 + x2 * x2 + x3 * x3;
        }
    }

    // ---- wave-wide scalar reductions (tot, sxx, sy): 64-lane butterflies ----
    float tl = sx.x + sx.y + sx.z + sx.w;   // per-lane contribution to tot
#pragma unroll
    for (int off = 32; off >= 1; off >>= 1) {
        tl  += __shfl_xor(tl,  off);
        sxx += __shfl_xor(sxx, off);
        yv  += __shfl_xor(yv,  off);        // becomes sy
    }

    // ---- combine row-halves for the per-column vectors ----
    sx.x  += __shfl_xor(sx.x,  32); sx.y  += __shfl_xor(sx.y,  32);
    sx.z  += __shfl_xor(sx.z,  32); sx.w  += __shfl_xor(sx.w,  32);
    sxy.x += __shfl_xor(sxy.x, 32); sxy.y += __shfl_xor(sxy.y, 32);
    sxy.z += __shfl_xor(sxy.z, 32); sxy.w += __shfl_xor(sxy.w, 32);

    // var = (sxx - tot^2/(n*D)) / (n*D - 1);  cov = (sxy - sx*sy/n)/(n-1)
    const float var = (sxx - tl * tl * (1.0f / 8192.0f)) * (1.0f / 8191.0f);
    const float iv  = 1.0f / var;
    const float c0  = yv * (1.0f / 64.0f);
    float4 rp;
    rp.x = (sxy.x - sx.x * c0) * (1.0f / 63.0f) * iv;
    rp.y = (sxy.y - sx.y * c0) * (1.0f / 63.0f) * iv;
    rp.z = (sxy.z - sx.z * c0) * (1.0f / 63.0f) * iv;
    rp.w = (sxy.w - sx.w * c0) * (1.0f / 63.0f) * iv;
    if (half == 0) ((float4*)rep)[g * 32 + c] = rp;   // 512B coalesced store
}

// ---------------------------------------------------------------------------
// Kernel 2: MLP head.  512 blocks x 256 threads, GPB=16 groups per block.
// Thread j = hidden unit; W1 row loads coalesced, reused 16x in registers.
// ---------------------------------------------------------------------------
__device__ __forceinline__ float fast_tanh(float v) {
    v = fminf(15.0f, fmaxf(-15.0f, v));
    float e = __expf(2.0f * v);
    return (e - 1.0f) / (e + 1.0f);
}

__device__ __forceinline__ float softplus_f(float v) {
    if (v > 15.0f) return v;
    return log1pf(__expf(v));
}

__global__ __launch_bounds__(256) void mlp_kernel(
    const float* __restrict__ rep, const float* __restrict__ W1,
    const float* __restrict__ b1, const float* __restrict__ W2,
    const float* __restrict__ b2, float* __restrict__ mix,
    float* __restrict__ scl, float* __restrict__ alp,
    float* __restrict__ bet)
{
    const int g0 = blockIdx.x * GPB;
    const int t = threadIdx.x;

    __shared__ __align__(16) float repL[GPB][ND];
    __shared__ float hL[GPB][NH + 1];     // +1 pad: kills 16-way bank conflict
    __shared__ float w2L[NH * NO];
    __shared__ float outL[GPB][NO];

    // stage rep tile: 2048 floats = 512 float4
    {
        const float4* rp4 = (const float4*)(rep + (size_t)g0 * ND);
        float4* dst = (float4*)&repL[0][0];
        dst[t] = rp4[t];
        dst[t + 256] = rp4[t + 256];
    }
    for (int i = t; i < NH * NO; i += 256) w2L[i] = W2[i];
    __syncthreads();

    // layer 1: h[g][t] = tanh(b1[t] + sum_d rep[g][d] * W1[d][t])
    float acc[GPB];
#pragma unroll
    for (int g = 0; g < GPB; ++g) acc[g] = 0.f;

    for (int d = 0; d < ND; d += 4) {
        float w0 = W1[(d + 0) * NH + t];
        float w1 = W1[(d + 1) * NH + t];
        float w2 = W1[(d + 2) * NH + t];
        float w3 = W1[(d + 3) * NH + t];
#pragma unroll
        for (int g = 0; g < GPB; ++g) {
            const float4 r4 = *(const float4*)&repL[g][d];   // wave-uniform broadcast
            acc[g] += r4.x * w0 + r4.y * w1 + r4.z * w2 + r4.w * w3;
        }
    }
    const float bb = b1[t];
#pragma unroll
    for (int g = 0; g < GPB; ++g) {
        hL[g][t] = fast_tanh(acc[g] + bb);
    }
    __syncthreads();

    // layer 2: 160 threads, one (group, output) pair each
    if (t < GPB * NO) {
        const int g = t / NO;
        const int k = t - g * NO;
        float s = b2[k];
#pragma unroll 8
        for (int j = 0; j < NH; ++j) s += hL[g][j] * w2L[j * NO + k];
        outL[g][k] = s;
    }
    __syncthreads();

    // epilogue: one thread per group
    if (t < GPB) {
        const int gg = g0 + t;
        float al = softplus_f(outL[t][0]) * 0.99f + 0.01f;
        float be = softplus_f(outL[t][1]) * 0.99f + 0.01f;
        float m = -1e30f;
#pragma unroll
        for (int k = 0; k < 8; ++k) m = fmaxf(m, outL[t][2 + k]);
        float e[8];
        float sum = 0.f;
#pragma unroll
        for (int k = 0; k < 8; ++k) { e[k] = __expf(outL[t][2 + k] - m); sum += e[k]; }
        float inv = 1.0f / sum;
#pragma unroll
        for (int k = 0; k < 8; ++k) mix[gg * 8 + k] = e[k] * inv;
        alp[gg] = al;
        bet[gg] = be;
        scl[gg] = sqrtf(be / al);
    }
}

// ---------------------------------------------------------------------------
extern "C" void kernel_launch(void* const* d_in, const int* in_sizes, int n_in,
                              void* d_out, int out_size, void* d_ws, size_t ws_size,
                              hipStream_t stream) {
    // inputs: 0=index (unused: groups are contiguous, 64 each), 1=x, 2=y,
    // 3=anchor_x, 4=anchor_y, 5=W1, 6=b1, 7=W2, 8=b2
    const float* x  = (const float*)d_in[1];
    const float* y  = (const float*)d_in[2];
    const float* ax = (const float*)d_in[3];
    const float* ay = (const float*)d_in[4];
    const float* W1 = (const float*)d_in[5];
    const float* b1 = (const float*)d_in[6];
    const float* W2 = (const float*)d_in[7];
    const float* b2 = (const float*)d_in[8];

    float* out = (float*)d_out;
    float* rep = out;                               // [G,128]
    float* mix = out + (size_t)NG * ND;             // [G,8]
    float* scl = mix + (size_t)NG * 8;              // [G,1]
    float* alp = scl + NG;                          // [G,1]
    float* bet = alp + NG;                          // [G,1]

    stats_kernel<<<NG / WPB, 256, 0, stream>>>(x, y, ax, ay, rep);
    mlp_kernel<<<NG / GPB, 256, 0, stream>>>(rep, W1, b1, W2, b2, mix, scl, alp, bet);
}

// Round 4
// 381.703 us; speedup vs baseline: 1.0521x; 1.0480x over previous
//
#include <hip/hip_runtime.h>
#include <math.h>

// Problem constants (fixed by reference setup_inputs)
#define NG   8192      // groups
#define NS   64        // samples per group
#define ND   128       // feature dim
#define NH   256       // hidden dim
#define NO   10        // K+2 outputs of layer 2
#define GPB  16        // groups per block in MLP kernel
#define WPB  4         // waves per block in stats kernel

// native vector type: __builtin_nontemporal_load rejects HIP_vector_type
typedef float floatx4 __attribute__((ext_vector_type(4)));

// ---------------------------------------------------------------------------
// Kernel 1: per-group stats -> rep.  One wave per group, barrier-free.
// Raw-moment formulation: accumulate S=Σx, Sxy=Σx·y_rel, S2=Σx² and apply
// anchor corrections in closed form (anchor cancels exactly in cov).
// 16-deep nontemporal float4 load batches; reductions via shfl only.
// ---------------------------------------------------------------------------
__global__ __launch_bounds__(256) void stats_kernel(
    const float* __restrict__ x, const float* __restrict__ y,
    const float* __restrict__ ax, const float* __restrict__ ay,
    float* __restrict__ rep)
{
    const int t    = threadIdx.x;
    const int w    = t >> 6;          // wave within block
    const int l    = t & 63;          // lane
    const int g    = blockIdx.x * WPB + w;
    const int c    = l & 31;          // float4 column (dims 4c..4c+3)
    const int half = l >> 5;          // row half (0: rows 0-31, 1: rows 32-63)

    __shared__ float yrelL[WPB][NS];  // per-wave y_rel staging (wave-synchronous)

    float yv = y[g * NS + l] - ay[g];
    yrelL[w][l] = yv;                 // same wave writes & reads -> no barrier

    const floatx4 a4 = ((const floatx4*)ax)[g * 32 + c];
    const floatx4* xg = (const floatx4*)x
                      + (size_t)g * (NS * 32) + (size_t)(half * 32) * 32 + c;

    floatx4 S   = (floatx4)(0.f);     // Σ x          (per column)
    floatx4 Sxy = (floatx4)(0.f);     // Σ x * y_rel  (per column)
    float   S2  = 0.f;                // Σ x·x  (lane's 4 cols, 32 rows)

#pragma unroll
    for (int ii = 0; ii < 2; ++ii) {
        floatx4 xv[16];
#pragma unroll
        for (int j = 0; j < 16; ++j)
            xv[j] = __builtin_nontemporal_load(&xg[(ii * 16 + j) * 32]);
#pragma unroll
        for (int j = 0; j < 16; ++j) {
            const float yr = yrelL[w][half * 32 + ii * 16 + j];  // 2-addr bcast
            S   += xv[j];
            Sxy += xv[j] * yr;
            S2  += xv[j].x * xv[j].x + xv[j].y * xv[j].y
                 + xv[j].z * xv[j].z + xv[j].w * xv[j].w;
        }
    }

    // ---- per-lane anchor corrections (use pre-combine, 32-row raw S) ----
    // sxx_lane = Σ(x-a)² over lane's 32 rows × 4 cols
    float sxxc = S2 - 2.0f * (a4.x * S.x + a4.y * S.y + a4.z * S.z + a4.w * S.w)
               + 32.0f * (a4.x * a4.x + a4.y * a4.y + a4.z * a4.z + a4.w * a4.w);
    // tot_lane = Σ sx over lane's 4 cols (32 rows): (Σ S) - 32·(Σ a)
    float totc = (S.x + S.y + S.z + S.w) - 32.0f * (a4.x + a4.y + a4.z + a4.w);

    // ---- wave-wide scalar reductions (tot, sxx, sy): 64-lane butterflies ----
#pragma unroll
    for (int off = 32; off >= 1; off >>= 1) {
        totc += __shfl_xor(totc, off);
        sxxc += __shfl_xor(sxxc, off);
        yv   += __shfl_xor(yv,   off);      // becomes sy = Σ y_rel
    }

    // ---- combine row-halves for the per-column vectors ----
    S.x   += __shfl_xor(S.x,   32); S.y   += __shfl_xor(S.y,   32);
    S.z   += __shfl_xor(S.z,   32); S.w   += __shfl_xor(S.w,   32);
    Sxy.x += __shfl_xor(Sxy.x, 32); Sxy.y += __shfl_xor(Sxy.y, 32);
    Sxy.z += __shfl_xor(Sxy.z, 32); Sxy.w += __shfl_xor(Sxy.w, 32);

    // var = (sxx - tot²/(n·D)) / (n·D - 1)
    const float var = (sxxc - totc * totc * (1.0f / 8192.0f)) * (1.0f / 8191.0f);
    const float iv  = 1.0f / var;
    // cov = (Σx_rel·y_rel - sx·sy/n)/(n-1) = (Sxy - S·sy/n)/(n-1)  [anchor cancels]
    const float c0  = yv * (1.0f / 64.0f);
    floatx4 rp;
    rp.x = (Sxy.x - S.x * c0) * (1.0f / 63.0f) * iv;
    rp.y = (Sxy.y - S.y * c0) * (1.0f / 63.0f) * iv;
    rp.z = (Sxy.z - S.z * c0) * (1.0f / 63.0f) * iv;
    rp.w = (Sxy.w - S.w * c0) * (1.0f / 63.0f) * iv;
    if (half == 0) ((floatx4*)rep)[g * 32 + c] = rp;   // 512B coalesced store
}

// ---------------------------------------------------------------------------
// Kernel 2: MLP head.  512 blocks x 256 threads, GPB=16 groups per block.
// ---------------------------------------------------------------------------
__device__ __forceinline__ float fast_tanh(float v) {
    v = fminf(15.0f, fmaxf(-15.0f, v));
    float e = __expf(2.0f * v);
    return (e - 1.0f) / (e + 1.0f);
}

__device__ __forceinline__ float softplus_f(float v) {
    if (v > 15.0f) return v;
    return log1pf(__expf(v));
}

__global__ __launch_bounds__(256) void mlp_kernel(
    const float* __restrict__ rep, const float* __restrict__ W1,
    const float* __restrict__ b1, const float* __restrict__ W2,
    const float* __restrict__ b2, float* __restrict__ mix,
    float* __restrict__ scl, float* __restrict__ alp,
    float* __restrict__ bet)
{
    const int g0 = blockIdx.x * GPB;
    const int t = threadIdx.x;

    __shared__ __align__(16) float repL[GPB][ND];
    __shared__ float hL[GPB][NH + 1];     // +1 pad: kills 16-way bank conflict
    __shared__ float w2L[NH * NO];
    __shared__ float outL[GPB][NO];

    {
        const float4* rp4 = (const float4*)(rep + (size_t)g0 * ND);
        float4* dst = (float4*)&repL[0][0];
        dst[t] = rp4[t];
        dst[t + 256] = rp4[t + 256];
    }
    for (int i = t; i < NH * NO; i += 256) w2L[i] = W2[i];
    __syncthreads();

    float acc[GPB];
#pragma unroll
    for (int g = 0; g < GPB; ++g) acc[g] = 0.f;

    for (int d = 0; d < ND; d += 4) {
        float w0 = W1[(d + 0) * NH + t];
        float w1 = W1[(d + 1) * NH + t];
        float w2 = W1[(d + 2) * NH + t];
        float w3 = W1[(d + 3) * NH + t];
#pragma unroll
        for (int g = 0; g < GPB; ++g) {
            const float4 r4 = *(const float4*)&repL[g][d];   // wave-uniform broadcast
            acc[g] += r4.x * w0 + r4.y * w1 + r4.z * w2 + r4.w * w3;
        }
    }
    const float bb = b1[t];
#pragma unroll
    for (int g = 0; g < GPB; ++g) {
        hL[g][t] = fast_tanh(acc[g] + bb);
    }
    __syncthreads();

    if (t < GPB * NO) {
        const int g = t / NO;
        const int k = t - g * NO;
        float s = b2[k];
#pragma unroll 8
        for (int j = 0; j < NH; ++j) s += hL[g][j] * w2L[j * NO + k];
        outL[g][k] = s;
    }
    __syncthreads();

    if (t < GPB) {
        const int gg = g0 + t;
        float al = softplus_f(outL[t][0]) * 0.99f + 0.01f;
        float be = softplus_f(outL[t][1]) * 0.99f + 0.01f;
        float m = -1e30f;
#pragma unroll
        for (int k = 0; k < 8; ++k) m = fmaxf(m, outL[t][2 + k]);
        float e[8];
        float sum = 0.f;
#pragma unroll
        for (int k = 0; k < 8; ++k) { e[k] = __expf(outL[t][2 + k] - m); sum += e[k]; }
        float inv = 1.0f / sum;
#pragma unroll
        for (int k = 0; k < 8; ++k) mix[gg * 8 + k] = e[k] * inv;
        alp[gg] = al;
        bet[gg] = be;
        scl[gg] = sqrtf(be / al);
    }
}

// ---------------------------------------------------------------------------
extern "C" void kernel_launch(void* const* d_in, const int* in_sizes, int n_in,
                              void* d_out, int out_size, void* d_ws, size_t ws_size,
                              hipStream_t stream) {
    // inputs: 0=index (unused: groups are contiguous, 64 each), 1=x, 2=y,
    // 3=anchor_x, 4=anchor_y, 5=W1, 6=b1, 7=W2, 8=b2
    const float* x  = (const float*)d_in[1];
    const float* y  = (const float*)d_in[2];
    const float* ax = (const float*)d_in[3];
    const float* ay = (const float*)d_in[4];
    const float* W1 = (const float*)d_in[5];
    const float* b1 = (const float*)d_in[6];
    const float* W2 = (const float*)d_in[7];
    const float* b2 = (const float*)d_in[8];

    float* out = (float*)d_out;
    float* rep = out;                               // [G,128]
    float* mix = out + (size_t)NG * ND;             // [G,8]
    float* scl = mix + (size_t)NG * 8;              // [G,1]
    float* alp = scl + NG;                          // [G,1]
    float* bet = alp + NG;                          // [G,1]

    stats_kernel<<<NG / WPB, 256, 0, stream>>>(x, y, ax, ay, rep);
    mlp_kernel<<<NG / GPB, 256, 0, stream>>>(rep, W1, b1, W2, b2, mix, scl, alp, bet);
}